// Round 4
// baseline (131.670 us; speedup 1.0000x reference)
//
#include <hip/hip_runtime.h>

// Problem constants
#define BATCH  4
#define SEQL   2048
#define DMODEL 1024
#define NST    16
#define CT     64            // chunk length T
#define NCH    (SEQL / CT)   // 32 chunks
#define QSEG   16            // tau segment length (4 segments per chunk)

// ws layout (float offsets)
#define WS_P     0           // P[sigma][m]   = (A^(T-1-sigma) B)[m]      : CT*16
#define WS_W     1024        // W[tau][m]     = (B^T A^(tau+1))[m]        : CT*16
#define WS_KV    2048        // kvext[127], kvext[63+d] = B^T A^d B, 0 for d<0
#define WS_APOW  2176        // Apow[m][k]    = (A^CT)[m][k]              : 256
#define WS_HIN   4096        // hin[b][j][d][m] = s_{j-1}                 : B*NCH*D*16

// ---------------------------------------------------------------------------
// Setup: block delta (0..64) computes A^delta in fp64 via binary powering,
// then emits its slice of the tables.
// ---------------------------------------------------------------------------
__global__ __launch_bounds__(256) void setup_tables(const float* __restrict__ A,
                                                    const float* __restrict__ Bv,
                                                    float* __restrict__ ws) {
    __shared__ double buf0[256], buf1[256], buf2[256], buf3[256];
    __shared__ double bd[16], vtmp[16];
    double* S  = buf0;
    double* R  = buf1;
    double* Ta = buf2;
    double* Tb = buf3;
    const int t  = threadIdx.x;
    const int i  = t >> 4;
    const int kk = t & 15;
    const int delta = blockIdx.x;   // 0..64

    S[t] = (double)A[t];
    R[t] = (i == kk) ? 1.0 : 0.0;
    if (t < 16) bd[t] = (double)Bv[t];
    __syncthreads();

    for (int sb = 0; sb < 7; ++sb) {
        if ((delta >> sb) & 1) {
            double acc = 0.0;
            #pragma unroll
            for (int l = 0; l < 16; ++l) acc += R[i * 16 + l] * S[l * 16 + kk];
            Ta[t] = acc;
            __syncthreads();
            double* tmp = R; R = Ta; Ta = tmp;
        }
        if (sb < 6) {
            double acc = 0.0;
            #pragma unroll
            for (int l = 0; l < 16; ++l) acc += S[i * 16 + l] * S[l * 16 + kk];
            Tb[t] = acc;
            __syncthreads();
            double* tmp = S; S = Tb; Tb = tmp;
        }
    }
    // R now holds A^delta (fp64)

    if (delta < CT) {
        if (t < 16) {   // m = t : P[CT-1-delta][m] = (A^delta B)[m]
            double acc = 0.0;
            #pragma unroll
            for (int k = 0; k < 16; ++k) acc += R[t * 16 + k] * bd[k];
            ws[WS_P + (CT - 1 - delta) * 16 + t] = (float)acc;
            vtmp[t] = acc;
        }
        __syncthreads();
        if (t == 0) {   // k_delta = B^T A^delta B
            double kd = 0.0;
            for (int m = 0; m < 16; ++m) kd += bd[m] * vtmp[m];
            ws[WS_KV + 63 + delta] = (float)kd;
        }
    }
    if (delta >= 1 && t < 16) {   // W[delta-1][m] = sum_n B[n] (A^delta)[n][m]
        double acc = 0.0;
        #pragma unroll
        for (int n = 0; n < 16; ++n) acc += bd[n] * R[n * 16 + t];
        ws[WS_W + (delta - 1) * 16 + t] = (float)acc;
    }
    if (delta == CT) ws[WS_APOW + t] = (float)R[t];   // A^CT carry matrix
    if (delta == 0 && t < 63) ws[WS_KV + t] = 0.0f;   // zero-pad negative lags
}

// ---------------------------------------------------------------------------
// K1: full chunk state, 512 blocks. 16-deep double-buffered x batches
// (213 ns compute per batch hides the ~375 ns HBM latency at 2 waves/SIMD).
// c_j[m] = sum_{sigma} P[sigma][m] x[sigma]
// ---------------------------------------------------------------------------
__global__ __launch_bounds__(256) void k1_chunkstate(const float* __restrict__ x,
                                                     const float* __restrict__ ws,
                                                     float* __restrict__ cbuf) {
    const int blk  = blockIdx.x;          // 512 blocks
    const int b    = blk >> 7;
    const int j    = (blk >> 2) & 31;
    const int dblk = blk & 3;
    const int d    = dblk * 256 + threadIdx.x;

    const float* P  = ws + WS_P;          // wave-uniform -> s_load
    const float* xp = x + ((size_t)(b * SEQL + j * CT)) * DMODEL + d;

    float c[16];
    #pragma unroll
    for (int m = 0; m < 16; ++m) c[m] = 0.0f;

    float xa[16], xb[16];
    #pragma unroll
    for (int s = 0; s < 16; ++s) xa[s] = xp[(size_t)s * DMODEL];

    #pragma unroll
    for (int g = 0; g < 4; ++g) {         // 4 batches of 16 sigma
        float* cur = (g & 1) ? xb : xa;
        float* nxt = (g & 1) ? xa : xb;
        if (g < 3) {
            #pragma unroll
            for (int s = 0; s < 16; ++s)
                nxt[s] = xp[(size_t)((g + 1) * 16 + s) * DMODEL];
        }
        #pragma unroll
        for (int s = 0; s < 16; ++s) {
            const int ss = g * 16 + s;
            #pragma unroll
            for (int m = 0; m < 16; ++m)
                c[m] = fmaf(P[ss * 16 + m], cur[s], c[m]);
        }
    }

    float4* outp = (float4*)(cbuf + (((size_t)(b * NCH + j) * DMODEL) + d) * 16);
    #pragma unroll
    for (int q = 0; q < 4; ++q)
        outp[q] = make_float4(c[4 * q], c[4 * q + 1], c[4 * q + 2], c[4 * q + 3]);
}

// ---------------------------------------------------------------------------
// K2: carry scan over chunks. Thread = (channel d, state component m).
// ALL 32 chunk partials prefetched upfront (independent, streams at BW),
// then the serial shfl chain runs from registers.
// s_j = Apow*s_{j-1} + c_j ; hin_j = s_{j-1}.
// ---------------------------------------------------------------------------
__global__ __launch_bounds__(256) void k2_carry(const float* __restrict__ cbuf,
                                                float* __restrict__ ws) {
    const int blk = blockIdx.x;           // 256 blocks
    const int b   = blk >> 6;
    const int d0  = (blk & 63) * 16;
    const int t   = threadIdx.x;
    const int m   = t & 15;
    const int ch  = t >> 4;
    const int d   = d0 + ch;
    const int laneBase = t & 48;          // 16-lane group base within wave

    const size_t base0   = (((size_t)(b * NCH) * DMODEL) + d) * 16 + m;
    const size_t jstride = (size_t)DMODEL * 16;

    float cpre[NCH];
    #pragma unroll
    for (int j = 0; j < NCH; ++j)
        cpre[j] = cbuf[base0 + (size_t)j * jstride];

    float Arow[16];
    #pragma unroll
    for (int k = 0; k < 16; ++k) Arow[k] = ws[WS_APOW + m * 16 + k];

    float* hin = ws + WS_HIN;
    float s = 0.0f;
    #pragma unroll
    for (int j = 0; j < NCH; ++j) {
        hin[base0 + (size_t)j * jstride] = s;
        float acc = cpre[j];
        #pragma unroll
        for (int k = 0; k < 16; ++k)
            acc = fmaf(Arow[k], __shfl(s, laneBase + k, 64), acc);
        s = acc;
    }
}

// ---------------------------------------------------------------------------
// K3: outputs. Each block handles COMPLEMENTARY tau tiles {PAIR, 3-PAIR} of
// one chunk -> every block does exactly 1280 conv-FMA + 512 correction-FMA
// (no tail imbalance). Single x-load stream over the big tile's range;
// small tile accumulates while ss < LIMS (compile-time guard).
// y[tau] = W[tau].h_in + sum_{s<=tau} k[tau-s] x[s]
// ---------------------------------------------------------------------------
template <int PAIR>
__device__ __forceinline__ void k3_body(const float* __restrict__ x,
                                        const float* __restrict__ ws,
                                        float* __restrict__ y,
                                        int b, int j, int d) {
    constexpr int TTB  = 3 - PAIR;            // big tile: 3 or 2
    constexpr int TTS  = PAIR;                // small tile: 0 or 1
    constexpr int LIMB = (TTB + 1) * QSEG;    // 64 or 48
    constexpr int LIMS = (TTS + 1) * QSEG;    // 16 or 32
    constexpr int NB   = LIMB / 16;           // 4 or 3 batches

    const float* W    = ws + WS_W;
    const float* kvB  = ws + WS_KV + 63 + TTB * QSEG;  // index by (i - ss)
    const float* kvS  = ws + WS_KV + 63 + TTS * QSEG;
    const float* hinp = ws + WS_HIN + (((size_t)(b * NCH + j) * DMODEL) + d) * 16;
    const float* xp   = x + ((size_t)(b * SEQL + j * CT)) * DMODEL + d;

    // issue h_in loads and first x batch together
    float4 hv[4];
    #pragma unroll
    for (int q = 0; q < 4; ++q) hv[q] = ((const float4*)hinp)[q];
    float xa[16], xb[16];
    #pragma unroll
    for (int s = 0; s < 16; ++s) xa[s] = xp[(size_t)s * DMODEL];

    float h[16];
    #pragma unroll
    for (int q = 0; q < 4; ++q) {
        h[4 * q] = hv[q].x; h[4 * q + 1] = hv[q].y;
        h[4 * q + 2] = hv[q].z; h[4 * q + 3] = hv[q].w;
    }

    float yvB[QSEG], yvS[QSEG];
    #pragma unroll
    for (int i = 0; i < QSEG; ++i) {          // corrections: W[tau] . h_in
        float aB = 0.0f, aS = 0.0f;
        #pragma unroll
        for (int mm = 0; mm < 16; ++mm) {
            aB = fmaf(W[(TTB * QSEG + i) * 16 + mm], h[mm], aB);
            aS = fmaf(W[(TTS * QSEG + i) * 16 + mm], h[mm], aS);
        }
        yvB[i] = aB; yvS[i] = aS;
    }

    #pragma unroll
    for (int g = 0; g < NB; ++g) {            // 16-wide double-buffered stream
        float* cur = (g & 1) ? xb : xa;
        float* nxt = (g & 1) ? xa : xb;
        if (g + 1 < NB) {
            #pragma unroll
            for (int s = 0; s < 16; ++s)
                nxt[s] = xp[(size_t)((g + 1) * 16 + s) * DMODEL];
        }
        #pragma unroll
        for (int s = 0; s < 16; ++s) {
            const int ss = g * 16 + s;
            float xv = cur[s];
            #pragma unroll
            for (int i = 0; i < QSEG; ++i)
                yvB[i] = fmaf(kvB[i - ss], xv, yvB[i]);
            if (ss < LIMS) {                  // compile-time per unrolled iter
                #pragma unroll
                for (int i = 0; i < QSEG; ++i)
                    yvS[i] = fmaf(kvS[i - ss], xv, yvS[i]);
            }
        }
    }

    float* ypB = y + ((size_t)(b * SEQL + j * CT + TTB * QSEG)) * DMODEL + d;
    float* ypS = y + ((size_t)(b * SEQL + j * CT + TTS * QSEG)) * DMODEL + d;
    #pragma unroll
    for (int i = 0; i < QSEG; ++i) {
        ypB[(size_t)i * DMODEL] = yvB[i];
        ypS[(size_t)i * DMODEL] = yvS[i];
    }
}

__global__ __launch_bounds__(256) void k3_output(const float* __restrict__ x,
                                                 const float* __restrict__ ws,
                                                 float* __restrict__ y) {
    const int blk  = blockIdx.x;          // 1024 blocks, all equal work
    const int b    = blk >> 8;
    const int j    = (blk >> 3) & 31;
    const int pair = (blk >> 2) & 1;
    const int dblk = blk & 3;
    const int d    = dblk * 256 + threadIdx.x;

    if (pair == 0) k3_body<0>(x, ws, y, b, j, d);
    else           k3_body<1>(x, ws, y, b, j, d);
}

// ---------------------------------------------------------------------------
extern "C" void kernel_launch(void* const* d_in, const int* in_sizes, int n_in,
                              void* d_out, int out_size, void* d_ws, size_t ws_size,
                              hipStream_t stream) {
    (void)in_sizes; (void)n_in; (void)out_size; (void)ws_size;
    const float* x  = (const float*)d_in[0];
    const float* A  = (const float*)d_in[1];
    const float* Bv = (const float*)d_in[2];
    float* out = (float*)d_out;
    float* ws  = (float*)d_ws;

    // c scratch lives in d_out (dead before K3 overwrites it with y);
    // h_in + tables in ws.
    setup_tables<<<65, 256, 0, stream>>>(A, Bv, ws);
    k1_chunkstate<<<512, 256, 0, stream>>>(x, ws, out);
    k2_carry<<<256, 256, 0, stream>>>(out, ws);
    k3_output<<<1024, 256, 0, stream>>>(x, ws, out);
}